// Round 7
// baseline (661.013 us; speedup 1.0000x reference)
//
#include <hip/hip_runtime.h>
#include <math.h>

#define B 2
#define L 2048
#define D 1024
#define H 16
#define DK 64
#define DFF 4096
#define EPS 1e-5f

typedef short short8 __attribute__((ext_vector_type(8)));
typedef short short4v __attribute__((ext_vector_type(4)));
typedef float float4v __attribute__((ext_vector_type(4)));
typedef unsigned int u32;

__device__ inline short f2bf(float f) {
    unsigned u = __builtin_bit_cast(unsigned, f);
    u += 0x7fffu + ((u >> 16) & 1u);  // round-to-nearest-even
    return (short)(u >> 16);
}

// async 16B global->LDS (dest = wave-uniform base + lane*16)
#define GLOAD_LDS16(gp, lp)                                                  \
    __builtin_amdgcn_global_load_lds(                                        \
        (const __attribute__((address_space(1))) u32*)(const void*)(gp),     \
        (__attribute__((address_space(3))) u32*)(void*)(lp), 16, 0, 0)

// ---------------- LayerNorm over (L,D) per batch ----------------------------

__global__ __launch_bounds__(256) void red_partial(const float* __restrict__ X,
                                                   float* __restrict__ part) {
    int b = blockIdx.y;
    const float4* p = (const float4*)(X + (size_t)b * L * D);
    float s = 0.f, ss = 0.f;
    for (int idx = blockIdx.x * 256 + threadIdx.x; idx < L * D / 4; idx += 256 * 256) {
        float4 v = p[idx];
        s += v.x + v.y + v.z + v.w;
        ss += v.x * v.x + v.y * v.y + v.z * v.z + v.w * v.w;
    }
    __shared__ float sh0[256], sh1[256];
    sh0[threadIdx.x] = s; sh1[threadIdx.x] = ss;
    __syncthreads();
    for (int o = 128; o; o >>= 1) {
        if (threadIdx.x < o) {
            sh0[threadIdx.x] += sh0[threadIdx.x + o];
            sh1[threadIdx.x] += sh1[threadIdx.x + o];
        }
        __syncthreads();
    }
    if (threadIdx.x == 0) {
        part[(b * 256 + blockIdx.x) * 2 + 0] = sh0[0];
        part[(b * 256 + blockIdx.x) * 2 + 1] = sh1[0];
    }
}

__global__ __launch_bounds__(256) void red_final(const float* __restrict__ part,
                                                 float* __restrict__ stats) {
    int b = blockIdx.x;
    float s = part[(b * 256 + threadIdx.x) * 2 + 0];
    float ss = part[(b * 256 + threadIdx.x) * 2 + 1];
    __shared__ float sh0[256], sh1[256];
    sh0[threadIdx.x] = s; sh1[threadIdx.x] = ss;
    __syncthreads();
    for (int o = 128; o; o >>= 1) {
        if (threadIdx.x < o) {
            sh0[threadIdx.x] += sh0[threadIdx.x + o];
            sh1[threadIdx.x] += sh1[threadIdx.x + o];
        }
        __syncthreads();
    }
    if (threadIdx.x == 0) {
        const float invN = 1.f / (float)(L * D);
        float mu = sh0[0] * invN;
        float var = sh1[0] * invN - mu * mu;
        stats[b * 2 + 0] = mu;
        stats[b * 2 + 1] = rsqrtf(var + EPS);
    }
}

__global__ __launch_bounds__(256) void ln_apply_bf(const float* __restrict__ X,
                                                   const float* __restrict__ W,
                                                   const float* __restrict__ Bb,
                                                   const float* __restrict__ stats,
                                                   short* __restrict__ Yn) {
    int b = blockIdx.y;
    float mu = stats[b * 2 + 0];
    float rstd = stats[b * 2 + 1];
    size_t e = (size_t)(blockIdx.x * 256 + threadIdx.x) * 4;
    const float4 xv = *(const float4*)(X + (size_t)b * L * D + e);
    const float4 wv = *(const float4*)(W + e);
    const float4 bv = *(const float4*)(Bb + e);
    short4v o;
    o[0] = f2bf((xv.x - mu) * rstd * wv.x + bv.x);
    o[1] = f2bf((xv.y - mu) * rstd * wv.y + bv.y);
    o[2] = f2bf((xv.z - mu) * rstd * wv.z + bv.z);
    o[3] = f2bf((xv.w - mu) * rstd * wv.w + bv.w);
    *(short4v*)(Yn + (size_t)b * L * D + e) = o;
}

__global__ __launch_bounds__(256) void convert_bf(const float* __restrict__ X,
                                                  short* __restrict__ Y) {
    size_t e = (size_t)(blockIdx.x * 256 + threadIdx.x) * 4;
    const float4 v = *(const float4*)(X + e);
    short4v o = {f2bf(v.x), f2bf(v.y), f2bf(v.z), f2bf(v.w)};
    *(short4v*)(Y + e) = o;
}

// W [K][N] fp32 -> WT [N][K] bf16
__global__ __launch_bounds__(256) void wt_transpose(const float* __restrict__ W,
                                                    short* __restrict__ WT,
                                                    int K, int N) {
    __shared__ short tile[32][33];
    const int t = threadIdx.x;
    const int tx = t & 31, ty = t >> 5;  // 32 x 8
    const int k0 = blockIdx.y * 32, n0 = blockIdx.x * 32;
#pragma unroll
    for (int i = 0; i < 4; ++i) {
        const int k = ty + i * 8;
        tile[k][tx] = f2bf(W[(size_t)(k0 + k) * N + n0 + tx]);
    }
    __syncthreads();
#pragma unroll
    for (int i = 0; i < 4; ++i) {
        const int n = ty + i * 8;
        WT[(size_t)(n0 + n) * K + k0 + tx] = tile[tx][n];
    }
}

// V half of kv buffer -> VT[b][h][d][key] (bf16), once per launch
#define SKV (2 * D)
__global__ __launch_bounds__(256) void v_transpose(const short* __restrict__ KVg,
                                                   short* __restrict__ VTg) {
    __shared__ short tile[64][72];
    const int t = threadIdx.x;
    const int kt = blockIdx.x;          // key tile (32)
    const int bh = blockIdx.y;          // b*H + h  (32)
    const int b = bh >> 4, h = bh & (H - 1);
#pragma unroll
    for (int rep = 0; rep < 2; ++rep) {
        const int lin = rep * 256 + t;
        const int j = lin >> 3;
        const int d8 = (lin & 7) * 8;
        const short8 v = *(const short8*)(KVg +
            (size_t)(b * L + kt * 64 + j) * SKV + D + h * DK + d8);
        *(short8*)&tile[j][d8] = v;
    }
    __syncthreads();
#pragma unroll
    for (int rep = 0; rep < 2; ++rep) {
        const int lin = rep * 256 + t;
        const int d = lin >> 3;
        const int j8 = (lin & 7) * 8;
        short8 o;
#pragma unroll
        for (int i = 0; i < 8; ++i) o[i] = tile[j8 + i][d];
        *(short8*)(VTg + (size_t)(bh * DK + d) * L + kt * 64 + j8) = o;
    }
}

// ---------------- bf16 MFMA GEMM, BM=BN=128 (m97 structure) -----------------
// Grid: x = m-tile, y = n-tile (consecutive blocks share the B/weight panel).
// flags: 1 = relu, 2 = bf16 output.

__global__ __launch_bounds__(256) void gemm_mfma(const short* __restrict__ A,
                                                 const short* __restrict__ BT,
                                                 const float* __restrict__ bias,
                                                 const float* __restrict__ Res,
                                                 void* __restrict__ Cout,
                                                 int M, int N, int K, int flags) {
    __shared__ short As[128 * 32];
    __shared__ short Bs[128 * 32];
    const int t = threadIdx.x;
    const int wave = t >> 6, lane = t & 63;
    const int m16 = lane & 15, q4 = lane >> 4;
    const int m0 = blockIdx.x * 128, n0 = blockIdx.y * 128;
    const int wm = (wave >> 1) * 64, wn = (wave & 1) * 64;

    float4v acc[4][4];
#pragma unroll
    for (int i = 0; i < 4; ++i)
#pragma unroll
        for (int j = 0; j < 4; ++j) acc[i][j] = (float4v){0.f, 0.f, 0.f, 0.f};

    for (int k0 = 0; k0 < K; k0 += 32) {
        __syncthreads();
#pragma unroll
        for (int pass = 0; pass < 2; ++pass) {
            const int idx = pass * 256 + t;
            const int row = idx >> 2;
            const int ko = (idx & 3) * 8;
            short* ldsA = &As[(pass * 256 + wave * 64) * 8];
            short* ldsB = &Bs[(pass * 256 + wave * 64) * 8];
            GLOAD_LDS16(A + (size_t)(m0 + row) * K + k0 + ko, ldsA);
            GLOAD_LDS16(BT + (size_t)(n0 + row) * K + k0 + ko, ldsB);
        }
        __syncthreads();

        short8 af[4], bf[4];
#pragma unroll
        for (int mi = 0; mi < 4; ++mi)
            af[mi] = *(const short8*)&As[(wm + mi * 16 + m16) * 32 + q4 * 8];
#pragma unroll
        for (int ni = 0; ni < 4; ++ni)
            bf[ni] = *(const short8*)&Bs[(wn + ni * 16 + m16) * 32 + q4 * 8];
#pragma unroll
        for (int mi = 0; mi < 4; ++mi)
#pragma unroll
            for (int ni = 0; ni < 4; ++ni)
                acc[mi][ni] = __builtin_amdgcn_mfma_f32_16x16x32_bf16(
                    af[mi], bf[ni], acc[mi][ni], 0, 0, 0);
    }

#pragma unroll
    for (int mi = 0; mi < 4; ++mi)
#pragma unroll
        for (int ni = 0; ni < 4; ++ni) {
            const int col = n0 + wn + ni * 16 + m16;
            const float bb = bias[col];
#pragma unroll
            for (int r = 0; r < 4; ++r) {
                const int row = m0 + wm + mi * 16 + q4 * 4 + r;
                float v = acc[mi][ni][r] + bb;
                if (Res) v += Res[(size_t)row * N + col];
                if (flags & 1) v = fmaxf(v, 0.f);
                if (flags & 2)
                    ((short*)Cout)[(size_t)row * N + col] = f2bf(v);
                else
                    ((float*)Cout)[(size_t)row * N + col] = v;
            }
        }
}

// ---------------- bf16 MFMA GEMM, BM=64 BN=128 ------------------------------

__global__ __launch_bounds__(256) void gemm_mfma_64(const short* __restrict__ A,
                                                    const short* __restrict__ BT,
                                                    const float* __restrict__ bias,
                                                    const float* __restrict__ Res,
                                                    void* __restrict__ Cout,
                                                    int M, int N, int K, int flags) {
    __shared__ short As[64 * 32];
    __shared__ short Bs[128 * 32];
    const int t = threadIdx.x;
    const int wave = t >> 6, lane = t & 63;
    const int m16 = lane & 15, q4 = lane >> 4;
    const int m0 = blockIdx.x * 64, n0 = blockIdx.y * 128;
    const int wm = (wave >> 1) * 32, wn = (wave & 1) * 64;

    float4v acc[2][4];
#pragma unroll
    for (int i = 0; i < 2; ++i)
#pragma unroll
        for (int j = 0; j < 4; ++j) acc[i][j] = (float4v){0.f, 0.f, 0.f, 0.f};

    for (int k0 = 0; k0 < K; k0 += 32) {
        __syncthreads();
        {   // A: 64x32 = 1 pass
            const int row = t >> 2;
            const int ko = (t & 3) * 8;
            short* ldsA = &As[(wave * 64) * 8];
            GLOAD_LDS16(A + (size_t)(m0 + row) * K + k0 + ko, ldsA);
        }
#pragma unroll
        for (int pass = 0; pass < 2; ++pass) {  // B: 128x32 = 2 passes
            const int idx = pass * 256 + t;
            const int row = idx >> 2;
            const int ko = (idx & 3) * 8;
            short* ldsB = &Bs[(pass * 256 + wave * 64) * 8];
            GLOAD_LDS16(BT + (size_t)(n0 + row) * K + k0 + ko, ldsB);
        }
        __syncthreads();

        short8 af[2], bf[4];
#pragma unroll
        for (int mi = 0; mi < 2; ++mi)
            af[mi] = *(const short8*)&As[(wm + mi * 16 + m16) * 32 + q4 * 8];
#pragma unroll
        for (int ni = 0; ni < 4; ++ni)
            bf[ni] = *(const short8*)&Bs[(wn + ni * 16 + m16) * 32 + q4 * 8];
#pragma unroll
        for (int mi = 0; mi < 2; ++mi)
#pragma unroll
            for (int ni = 0; ni < 4; ++ni)
                acc[mi][ni] = __builtin_amdgcn_mfma_f32_16x16x32_bf16(
                    af[mi], bf[ni], acc[mi][ni], 0, 0, 0);
    }

#pragma unroll
    for (int mi = 0; mi < 2; ++mi)
#pragma unroll
        for (int ni = 0; ni < 4; ++ni) {
            const int col = n0 + wn + ni * 16 + m16;
            const float bb = bias[col];
#pragma unroll
            for (int r = 0; r < 4; ++r) {
                const int row = m0 + wm + mi * 16 + q4 * 4 + r;
                float v = acc[mi][ni][r] + bb;
                if (Res) v += Res[(size_t)row * N + col];
                if (flags & 1) v = fmaxf(v, 0.f);
                if (flags & 2)
                    ((short*)Cout)[(size_t)row * N + col] = f2bf(v);
                else
                    ((float*)Cout)[(size_t)row * N + col] = v;
            }
        }
}

// ---------------- MFMA flash attention v3: barrier-free ---------------------
// K B-frags read DIRECTLY from kvb rows (16B contiguous), V B-frags directly
// from pre-transposed VT rows. Only P round-trips through LDS (per-wave band,
// same-wave DS ordering — NO __syncthreads in the K-loop, no vmcnt(0) drain).
// tril-ZERO semantics: masked p = exp(0) = 1; no running max (|s| <~ 3).

#define ASTR 72
#define EXPC 0.180336880f  // 0.125 * log2(e)

__global__ __launch_bounds__(256) void attn_mfma(const short* __restrict__ Qg,
                                                 const short* __restrict__ KVg,
                                                 const short* __restrict__ VTg,
                                                 short* __restrict__ O) {
    __shared__ short Pb[64 * ASTR];  // Pb[i][j], j-blocks XORed by (i>>3)

    const int t = threadIdx.x;
    const int wave = t >> 6;
    const int lane = t & 63;
    const int m16 = lane & 15;
    const int q4 = lane >> 4;

    const int qt = blockIdx.x & 31;
    const int bh = blockIdx.x >> 5;
    const int h = bh & (H - 1);
    const int b = bh >> 4;
    const size_t baseQ = (size_t)b * L * D + (size_t)h * DK;
    const int q0 = qt * 64;
    const int rowA = q0 + wave * 16 + m16;

    // K row pointer base for this lane's B-frag rows: key = kt0 + f*16 + m16
    const short* Kbase = KVg + (size_t)(b * L) * SKV + h * DK + (size_t)m16 * SKV + q4 * 8;
    // VT row pointer base: d = f*16 + m16
    const short* Vbase = VTg + (size_t)(bh * DK + m16) * L + q4 * 8;

    short8 qf[2];
#pragma unroll
    for (int kc = 0; kc < 2; ++kc)
        qf[kc] = *(const short8*)(Qg + baseQ + (size_t)rowA * D + kc * 32 + q4 * 8);

    float lsum[4] = {0.f, 0.f, 0.f, 0.f};
    float4v acc[4];
#pragma unroll
    for (int f = 0; f < 4; ++f) acc[f] = (float4v){0.f, 0.f, 0.f, 0.f};

    const int ig = q0 + wave * 16 + q4 * 4;  // this lane's first C-row
    const int prow2 = wave * 16 + m16;
    const int pg2 = prow2 >> 3;

    for (int kt0 = 0; kt0 < L; kt0 += 64) {
        // ---- scores: K frags straight from global (L1/L2-served) ----
        float pv[4][4];
#pragma unroll
        for (int f = 0; f < 4; ++f) {
            const short* kp = Kbase + (size_t)(kt0 + f * 16) * SKV;
            const short8 k0 = *(const short8*)kp;
            const short8 k1 = *(const short8*)(kp + 32);
            float4v sv = {0.f, 0.f, 0.f, 0.f};
            sv = __builtin_amdgcn_mfma_f32_16x16x32_bf16(qf[0], k0, sv, 0, 0, 0);
            sv = __builtin_amdgcn_mfma_f32_16x16x32_bf16(qf[1], k1, sv, 0, 0, 0);
            const int jg = kt0 + f * 16 + m16;
#pragma unroll
            for (int r = 0; r < 4; ++r)
                pv[f][r] = (jg <= ig + r) ? exp2f(sv[r] * EXPC) : 1.0f;
        }
#pragma unroll
        for (int r = 0; r < 4; ++r)
            lsum[r] += pv[0][r] + pv[1][r] + pv[2][r] + pv[3][r];

        // ---- P (C-layout) -> LDS bf16, swizzled (per-wave band) ----
#pragma unroll
        for (int f = 0; f < 4; ++f)
#pragma unroll
            for (int r = 0; r < 4; ++r) {
                const int prow = wave * 16 + q4 * 4 + r;
                const int col = f * 16 + m16;
                const int addr = prow * ASTR + ((((col >> 3) ^ (prow >> 3)) << 3) | (col & 7));
                Pb[addr] = f2bf(pv[f][r]);
            }

        // ---- PV: P A-frags from LDS, V B-frags straight from VT global ----
#pragma unroll
        for (int kc = 0; kc < 2; ++kc) {
            const short8 pf = *(const short8*)&Pb[prow2 * ASTR + (((kc * 4 + q4) ^ pg2) << 3)];
#pragma unroll
            for (int f = 0; f < 4; ++f) {
                const short8 vf = *(const short8*)(Vbase + (size_t)(f * 16) * L + kt0 + kc * 32);
                acc[f] = __builtin_amdgcn_mfma_f32_16x16x32_bf16(pf, vf, acc[f], 0, 0, 0);
            }
        }
    }

    float inv[4];
#pragma unroll
    for (int r = 0; r < 4; ++r) {
        float s = lsum[r];
#pragma unroll
        for (int off = 1; off < 16; off <<= 1) s += __shfl_xor(s, off);
        inv[r] = 1.0f / s;
    }

#pragma unroll
    for (int f = 0; f < 4; ++f)
#pragma unroll
        for (int r = 0; r < 4; ++r) {
            const int i = q0 + wave * 16 + q4 * 4 + r;
            O[baseQ + (size_t)i * D + f * 16 + m16] = f2bf(acc[f][r] * inv[r]);
        }
}

// ---------------- launch ----------------------------------------------------

extern "C" void kernel_launch(void* const* d_in, const int* in_sizes, int n_in,
                              void* d_out, int out_size, void* d_ws, size_t ws_size,
                              hipStream_t stream) {
    const float* x    = (const float*)d_in[0];
    const float* y    = (const float*)d_in[1];
    const float* Wq   = (const float*)d_in[2];
    const float* bq   = (const float*)d_in[3];
    const float* Wk   = (const float*)d_in[4];
    const float* bk   = (const float*)d_in[5];
    const float* Wv   = (const float*)d_in[6];
    const float* bv   = (const float*)d_in[7];
    const float* Wo   = (const float*)d_in[8];
    const float* bo   = (const float*)d_in[9];
    const float* W1   = (const float*)d_in[10];
    const float* b1   = (const float*)d_in[11];
    const float* W2   = (const float*)d_in[12];
    const float* b2   = (const float*)d_in[13];
    const float* ln1w = (const float*)d_in[14];
    const float* ln1b = (const float*)d_in[15];
    const float* ln2w = (const float*)d_in[16];
    const float* ln2b = (const float*)d_in[17];
    float* out = (float*)d_out;

    const size_t F = (size_t)B * L * D;      // 4,194,304
    char* p = (char*)d_ws;
    short* xb    = (short*)p; p += F * 2;
    short* ynb   = (short*)p; p += F * 2;
    short* qb    = (short*)p; p += F * 2;
    short* kvb   = (short*)p; p += 2 * F * 2;     // [M][2048]: k | v
    short* vtb   = (short*)p; p += F * 2;         // VT[b][h][d][key]
    short* aob   = (short*)p; p += F * 2;
    short* y1nb  = (short*)p; p += F * 2;
    short* hb    = (short*)p; p += (size_t)B * L * DFF * 2;
    float* y1    = (float*)p; p += F * 4;
    short* WqT   = (short*)p; p += (size_t)D * D * 2;
    short* WkvT  = (short*)p; p += (size_t)D * 2 * D * 2;  // [2048][1024]
    short* WoT   = (short*)p; p += (size_t)D * D * 2;
    short* W1T   = (short*)p; p += (size_t)D * DFF * 2;
    short* W2T   = (short*)p; p += (size_t)D * DFF * 2;
    float* biaskv= (float*)p; p += 2 * D * 4;
    float* part  = (float*)p; p += B * 256 * 2 * 4;
    float* stats = (float*)p;

    const int M = B * L;  // 4096

    // weight transpose+convert (once per launch)
    wt_transpose<<<dim3(D / 32, D / 32), 256, 0, stream>>>(Wq, WqT, D, D);
    wt_transpose<<<dim3(D / 32, D / 32), 256, 0, stream>>>(Wk, WkvT, D, D);
    wt_transpose<<<dim3(D / 32, D / 32), 256, 0, stream>>>(Wv, WkvT + (size_t)D * D, D, D);
    wt_transpose<<<dim3(D / 32, D / 32), 256, 0, stream>>>(Wo, WoT, D, D);
    wt_transpose<<<dim3(DFF / 32, D / 32), 256, 0, stream>>>(W1, W1T, D, DFF);
    wt_transpose<<<dim3(D / 32, DFF / 32), 256, 0, stream>>>(W2, W2T, DFF, D);
    hipMemcpyAsync(biaskv,     bk, D * sizeof(float), hipMemcpyDeviceToDevice, stream);
    hipMemcpyAsync(biaskv + D, bv, D * sizeof(float), hipMemcpyDeviceToDevice, stream);

    // x -> bf16
    convert_bf<<<dim3(F / 1024), 256, 0, stream>>>(x, xb);

    // LN1(y) -> ynb (bf16)
    red_partial<<<dim3(256, B), 256, 0, stream>>>(y, part);
    red_final<<<dim3(B), 256, 0, stream>>>(part, stats);
    ln_apply_bf<<<dim3(L * D / 1024, B), 256, 0, stream>>>(y, ln1w, ln1b, stats, ynb);

    // q = x@Wq (bf16); kv = ynb@[Wk|Wv] fused (bf16)
    gemm_mfma_64<<<dim3(M / 64, D / 128), 256, 0, stream>>>(xb, WqT, bq, nullptr, qb, M, D, D, 2);
    gemm_mfma<<<dim3(M / 128, 2 * D / 128), 256, 0, stream>>>(ynb, WkvT, biaskv, nullptr, kvb, M, 2 * D, D, 2);

    // V -> VT (per-head transposed copy)
    v_transpose<<<dim3(L / 64, B * H), 256, 0, stream>>>(kvb, vtb);

    // attention -> aob (bf16)
    attn_mfma<<<dim3(B * H * 32), 256, 0, stream>>>(qb, kvb, vtb, aob);

    // y1 = y + attn@Wo + bo (fp32)
    gemm_mfma_64<<<dim3(M / 64, D / 128), 256, 0, stream>>>(aob, WoT, bo, y, y1, M, D, D, 0);

    // LN2(y1) -> y1nb (bf16)
    red_partial<<<dim3(256, B), 256, 0, stream>>>(y1, part);
    red_final<<<dim3(B), 256, 0, stream>>>(part, stats);
    ln_apply_bf<<<dim3(L * D / 1024, B), 256, 0, stream>>>(y1, ln2w, ln2b, stats, y1nb);

    // h = relu(y1n@W1 + b1) (bf16)
    gemm_mfma<<<dim3(M / 128, DFF / 128), 256, 0, stream>>>(y1nb, W1T, b1, nullptr, hb, M, DFF, D, 3);

    // out = y1 + h@W2 + b2 (fp32)
    gemm_mfma_64<<<dim3(M / 64, D / 128), 256, 0, stream>>>(hb, W2T, b2, y1, out, M, D, DFF, 0);
}